// Round 14
// baseline (3083.110 us; speedup 1.0000x reference)
//
#include <hip/hip_runtime.h>
#include <stdint.h>

#define H   512
#define B   64
#define T   512
#define E   256
#define G3  1536   // 3*H
#define CT  64     // time-chunk length (T/CT = 8 chunks)
#define NBG 4      // independent batch groups (16 batches each)
#define NUG 32     // unit blocks per direction (16 units each)

typedef short s16;
typedef unsigned short u16;
typedef unsigned int u32;
typedef __attribute__((ext_vector_type(8))) short   short8;
typedef __attribute__((ext_vector_type(4))) float   f32x4;
typedef __attribute__((ext_vector_type(4))) unsigned int u32x4;
typedef __attribute__((ext_vector_type(2))) unsigned int u32x2;
typedef __bf16 bf8_t __attribute__((ext_vector_type(8)));

__device__ __forceinline__ u16 f2b(float f) {
    union { float f; unsigned int i; } v; v.f = f;
    unsigned int r = v.i + 0x7FFF + ((v.i >> 16) & 1);
    return (u16)(r >> 16);
}
__device__ __forceinline__ float sigm(float x)  { return 1.f / (1.f + __expf(-x)); }
__device__ __forceinline__ float tanhs(float x) { return 1.f - 2.f / (1.f + __expf(2.f * x)); }

// ------------------------------------------------------- fused prep: weight cvt + layer-0 init
// Replaces 4 k_cvt launches + the first k_init (saves 4 dispatch gaps).
__global__ void k_prep(const float* __restrict__ wih0, const float* __restrict__ wih1,
                       const float* __restrict__ whh0, const float* __restrict__ whh1,
                       u16* __restrict__ wih0b, u16* __restrict__ wih1b,
                       u16* __restrict__ whh0b, u16* __restrict__ whh1b,
                       float* __restrict__ h32, u32* __restrict__ slots) {
    long i = (long)blockIdx.x * 256 + threadIdx.x;
    long stride = (long)gridDim.x * 256;
    for (long j = i; j < 786432L;  j += stride) wih0b[j] = f2b(wih0[j]);
    for (long j = i; j < 3145728L; j += stride) wih1b[j] = f2b(wih1[j]);
    for (long j = i; j < 1572864L; j += stride) whh0b[j] = f2b(whh0[j]);
    for (long j = i; j < 1572864L; j += stride) whh1b[j] = f2b(whh1[j]);
    for (long j = i; j < 131072L;  j += stride) slots[j] = 0;     // stamp 0 + h_0 = 0
    for (long j = i; j < 65536L;   j += stride) h32[j] = 0.f;     // fp32 carry
}

// ------------------------------------------------------- init h32/slots (between layers)
__global__ void k_init(float* __restrict__ h32, u32* __restrict__ slots) {
    int i = blockIdx.x * 256 + threadIdx.x;      // 131072 u32 = 512 KB slot buffer
    slots[i] = 0;                                 // stamp 0 + h=0 (initial state h_0)
    if (i < 65536) h32[i] = 0.f;                 // 2 dirs * B*H fp32 carry
}

// ------------------------------------------------------- xg chunk GEMM (MFMA)
// Writes xgT[d][tl][n][b] (fp32) = A[b,t,:K] . Wbf[d][n][:K] + bih[d][n]
// m-mapping: b = m&63, tl = m>>6 (t = t0(d,c)+tl). MFMA operands are SWAPPED
// (first = B-rows) so D-cols carry m -> coalesced C stores. (Unchanged.)
#define BM 128
#define BN 128
#define BK 32

__global__ __launch_bounds__(256)
void k_gemm_xg(const int* __restrict__ sent, const void* __restrict__ Abuf, int aIsF32,
               const u16* __restrict__ Wbf, const float* __restrict__ bih,
               float* __restrict__ xgT, int K, int c) {
    int d  = blockIdx.z;
    int t0 = d ? (T - (c + 1) * CT) : c * CT;
    const u16* Bw = Wbf + (long)d * G3 * K;
    const float* bias = bih + (long)d * G3;
    float* C = xgT + (long)d * (long)CT * G3 * B;

    __shared__ __align__(16) s16 lA[BM * BK];
    __shared__ __align__(16) s16 lB[BN * BK];

    int tid  = threadIdx.x;
    int lane = tid & 63;
    int wv   = tid >> 6;
    int wm   = wv >> 1, wn = wv & 1;
    int q    = lane >> 4, r16 = lane & 15;

    long m0 = (long)blockIdx.x * BM;
    long n0 = (long)blockIdx.y * BN;

    const float* rowAf[2];
    const s16*   rowAh[2];
    const u16*   rowB[2];
    #pragma unroll
    for (int i = 0; i < 2; i++) {
        int ch = tid + i * 256;
        int r  = ch >> 2, cc = (ch & 3) * 8;
        long m = m0 + r;
        int  bb_ = (int)(m & 63), tl = (int)(m >> 6);   // m = (tl<<6)|b
        int  t  = t0 + tl;
        if (aIsF32) rowAf[i] = (const float*)Abuf + (long)sent[bb_ * T + t] * K + cc;
        else        rowAh[i] = (const s16*)Abuf + ((long)bb_ * T + t) * K + cc;
        rowB[i] = Bw + (n0 + r) * K + cc;
    }

    f32x4 acc[4][4];
    #pragma unroll
    for (int i = 0; i < 4; i++)
        #pragma unroll
        for (int j = 0; j < 4; j++) acc[i][j] = (f32x4){0.f, 0.f, 0.f, 0.f};

    for (long k0 = 0; k0 < K; k0 += BK) {
        #pragma unroll
        for (int i = 0; i < 2; i++) {
            if (aIsF32) {
                float4 v0 = *(const float4*)(rowAf[i] + k0);
                float4 v1 = *(const float4*)(rowAf[i] + k0 + 4);
                short8 pk;
                pk[0] = (s16)f2b(v0.x); pk[1] = (s16)f2b(v0.y);
                pk[2] = (s16)f2b(v0.z); pk[3] = (s16)f2b(v0.w);
                pk[4] = (s16)f2b(v1.x); pk[5] = (s16)f2b(v1.y);
                pk[6] = (s16)f2b(v1.z); pk[7] = (s16)f2b(v1.w);
                ((short8*)lA)[tid + i * 256] = pk;
            } else {
                ((short8*)lA)[tid + i * 256] = *(const short8*)(rowAh[i] + k0);
            }
            ((short8*)lB)[tid + i * 256] = *(const short8*)((const s16*)rowB[i] + k0);
        }
        __syncthreads();

        bf8_t af[4], bf[4];
        #pragma unroll
        for (int mt = 0; mt < 4; mt++)
            af[mt] = ((const bf8_t*)lA)[(wm * 64 + mt * 16 + r16) * 4 + q];
        #pragma unroll
        for (int nt = 0; nt < 4; nt++)
            bf[nt] = ((const bf8_t*)lB)[(wn * 64 + nt * 16 + r16) * 4 + q];
        #pragma unroll
        for (int mt = 0; mt < 4; mt++)
            #pragma unroll
            for (int nt = 0; nt < 4; nt++)
                acc[mt][nt] = __builtin_amdgcn_mfma_f32_16x16x32_bf16(
                                  bf[nt], af[mt], acc[mt][nt], 0, 0, 0);   // swapped
        __syncthreads();
    }

    // D layout (swapped): row (q*4+rg) -> n-sub, col (r16) -> m-sub
    #pragma unroll
    for (int nt = 0; nt < 4; nt++) {
        f32x4 bv = *(const f32x4*)(bias + n0 + wn * 64 + nt * 16 + q * 4);
        #pragma unroll
        for (int mt = 0; mt < 4; mt++) {
            long m = m0 + wm * 64 + mt * 16 + r16;
            long tl = m >> 6, b = m & 63;
            #pragma unroll
            for (int rg = 0; rg < 4; rg++) {
                long n = n0 + wn * 64 + nt * 16 + q * 4 + rg;
                C[(tl * G3 + n) * B + b] = acc[mt][nt][rg] + bv[rg];
            }
        }
    }
}

// bulk load macro: 32 x dwordx4, each instr 1024 lane-contiguous bytes, scope SC
#define BULK(SC) \
    asm volatile( \
        "global_load_dwordx4 %0,  %16, off " SC "\n\t" \
        "global_load_dwordx4 %1,  %16, off offset:1024 " SC "\n\t" \
        "global_load_dwordx4 %2,  %16, off offset:2048 " SC "\n\t" \
        "global_load_dwordx4 %3,  %16, off offset:3072 " SC "\n\t" \
        "global_load_dwordx4 %4,  %17, off " SC "\n\t" \
        "global_load_dwordx4 %5,  %17, off offset:1024 " SC "\n\t" \
        "global_load_dwordx4 %6,  %17, off offset:2048 " SC "\n\t" \
        "global_load_dwordx4 %7,  %17, off offset:3072 " SC "\n\t" \
        "global_load_dwordx4 %8,  %18, off " SC "\n\t" \
        "global_load_dwordx4 %9,  %18, off offset:1024 " SC "\n\t" \
        "global_load_dwordx4 %10, %18, off offset:2048 " SC "\n\t" \
        "global_load_dwordx4 %11, %18, off offset:3072 " SC "\n\t" \
        "global_load_dwordx4 %12, %19, off " SC "\n\t" \
        "global_load_dwordx4 %13, %19, off offset:1024 " SC "\n\t" \
        "global_load_dwordx4 %14, %19, off offset:2048 " SC "\n\t" \
        "global_load_dwordx4 %15, %19, off offset:3072 " SC \
        : "=&v"(p0),"=&v"(p1),"=&v"(p2),"=&v"(p3), \
          "=&v"(p4),"=&v"(p5),"=&v"(p6),"=&v"(p7), \
          "=&v"(p8),"=&v"(p9),"=&v"(p10),"=&v"(p11), \
          "=&v"(p12),"=&v"(p13),"=&v"(p14),"=&v"(p15) \
        : "v"(qa0), "v"(qa1), "v"(qa2), "v"(qa3) \
        : "memory"); \
    asm volatile( \
        "global_load_dwordx4 %0,  %16, off " SC "\n\t" \
        "global_load_dwordx4 %1,  %16, off offset:1024 " SC "\n\t" \
        "global_load_dwordx4 %2,  %16, off offset:2048 " SC "\n\t" \
        "global_load_dwordx4 %3,  %16, off offset:3072 " SC "\n\t" \
        "global_load_dwordx4 %4,  %17, off " SC "\n\t" \
        "global_load_dwordx4 %5,  %17, off offset:1024 " SC "\n\t" \
        "global_load_dwordx4 %6,  %17, off offset:2048 " SC "\n\t" \
        "global_load_dwordx4 %7,  %17, off offset:3072 " SC "\n\t" \
        "global_load_dwordx4 %8,  %18, off " SC "\n\t" \
        "global_load_dwordx4 %9,  %18, off offset:1024 " SC "\n\t" \
        "global_load_dwordx4 %10, %18, off offset:2048 " SC "\n\t" \
        "global_load_dwordx4 %11, %18, off offset:3072 " SC "\n\t" \
        "global_load_dwordx4 %12, %19, off " SC "\n\t" \
        "global_load_dwordx4 %13, %19, off offset:1024 " SC "\n\t" \
        "global_load_dwordx4 %14, %19, off offset:2048 " SC "\n\t" \
        "global_load_dwordx4 %15, %19, off offset:3072 " SC "\n\t" \
        "s_waitcnt vmcnt(0)" \
        : "=&v"(p16),"=&v"(p17),"=&v"(p18),"=&v"(p19), \
          "=&v"(p20),"=&v"(p21),"=&v"(p22),"=&v"(p23), \
          "=&v"(p24),"=&v"(p25),"=&v"(p26),"=&v"(p27), \
          "=&v"(p28),"=&v"(p29),"=&v"(p30),"=&v"(p31) \
        : "v"(qa4), "v"(qa5), "v"(qa6), "v"(qa7) \
        : "memory");

// ------------------------------------------------------- wave-autonomous chunk recurrence
// 1-D grid of 256 single-wave blocks: dom = bid&7 -> (d,bg); ug = bid>>3.
// Under round-robin block->XCD placement each domain's 32 waves share ONE XCD,
// so slot traffic can stay in that XCD's L2. FAIL-SAFE locality:
//  - producers DUAL-STORE each slot: sc0 (fast, local L2) then sc0 sc1
//    (durable, MALL) — identical bytes, fire-and-forget.
//  - consumers start with sc0 bulk reads; dual-stamp verify rejects stale or
//    partial data; after 8 fails the wave STICKILY escalates to sc0 sc1 reads
//    (= R11's proven path). [R13 lesson: this scheme is only used with the
//    single-XCD &7 domain mapping — the 2-XCD variant failed correctness.]
// Slot layout/verify/retry semantics unchanged from R11/R12.
__global__ __launch_bounds__(64, 1)
void k_chunk(const u16* __restrict__ Whhbf, const float* __restrict__ bhh,
             const float* __restrict__ xgT, float* __restrict__ h32,
             u32* __restrict__ slots, int c, u16* __restrict__ x1out, int writeX1) {
    int bid = blockIdx.x;
    int dom = bid & 7;                   // sync domain: one XCD under round-robin
    int ug  = bid >> 3;                  // unit group: units ug*16..+15
    int d   = dom >> 2;
    int bg  = dom & 3;
    int lane = threadIdx.x;              // 0..63
    int q = lane >> 4, cc = lane & 15;
    int u0 = ug * 16;
    int bgl = bg * 16 + cc;              // this lane's batch (D-col side)

    const u16* W    = Whhbf + (long)d * G3 * H;
    const float* bb = bhh + (long)d * G3;
    const float* xgf = xgT + (long)d * (long)CT * G3 * B;
    float* h32d = h32 + (long)d * B * H;
    char* slotbase = (char*)slots;

    // ---- weight slice as registers (A-frag; compiler remats to cached loads) ----
    bf8_t w[3][16];
    #pragma unroll
    for (int gate = 0; gate < 3; gate++)
        #pragma unroll
        for (int kc = 0; kc < 16; kc++)
            w[gate][kc] = *(const bf8_t*)(W + (long)(gate * H + u0 + cc) * H + kc * 32 + q * 8);

    // per-unit biases, f32x4 over rg (units u0+q*4..+3)
    f32x4 brv = *(const f32x4*)(bb + u0 + q * 4);
    f32x4 bzv = *(const f32x4*)(bb + H + u0 + q * 4);
    f32x4 bnv = *(const f32x4*)(bb + 2 * H + u0 + q * 4);

    // fp32 h-carry: lane holds h[b=bgl][u0+q*4+rg] -> f32x4
    f32x4 hp = *(const f32x4*)(h32d + (long)bgl * H + u0 + q * 4);

    // producer slot byte offset (within a 32KB (d,parity,bg) block)
    int jw = ug * 4 + q;                 // unit quad index of this lane's 4 units
    long off_wr = (long)((jw >> 3) * 2 + (jw & 1)) * 1024
                + (long)((jw >> 1) & 3) * 256 + cc * 16;

    int base = c * CT;
    bool fast = true;                    // sticky: escalate to sc1 reads on trouble

    for (int sl = 0; sl < CT; sl++) {
        int s    = base + sl;
        int tl   = d ? (CT - 1 - sl) : sl;
        int time = d ? (T - 1 - s) : s;
        int tgt  = s;
        u32 st1  = (u32)(s + 1);

        // xg loads: issued first; latency hidden under the bulk RT.
        const float* xgb = xgf + ((long)tl * G3 + u0 + q * 4) * B + bgl;
        float xr[4], xz[4], xn[4];
        #pragma unroll
        for (int jj = 0; jj < 4; jj++) {
            xr[jj] = xgb[(long)jj * B];
            xz[jj] = xgb[(long)H * B + (long)jj * B];
            xn[jj] = xgb[(long)2 * H * B + (long)jj * B];
        }

        const char* domb = slotbase + (long)(((d * 2 + (s & 1)) * 4 + bg) * 32768);
        const char* pb  = domb + lane * 16;
        const char* qa0 = pb;
        const char* qa1 = pb + 4096;
        const char* qa2 = pb + 8192;
        const char* qa3 = pb + 12288;
        const char* qa4 = pb + 16384;
        const char* qa5 = pb + 20480;
        const char* qa6 = pb + 24576;
        const char* qa7 = pb + 28672;
        u32x4 p0,p1,p2,p3,p4,p5,p6,p7,p8,p9,p10,p11,p12,p13,p14,p15;
        u32x4 p16,p17,p18,p19,p20,p21,p22,p23,p24,p25,p26,p27,p28,p29,p30,p31;

        int fails = 0;
        for (;;) {
            // ---- fused bulk load + full stamp verify (retry on straggler) ----
            if (fast) { BULK("sc0") }
            else      { BULK("sc0 sc1") }
            __builtin_amdgcn_sched_barrier(0);   // stamp checks must not hoist above vmcnt
            int mn = min((int)p0[1], (int)p0[3]);
            #define MN2(x) mn = min(mn, min((int)x[1], (int)x[3]));
            MN2(p1)  MN2(p2)  MN2(p3)  MN2(p4)  MN2(p5)  MN2(p6)  MN2(p7)
            MN2(p8)  MN2(p9)  MN2(p10) MN2(p11) MN2(p12) MN2(p13) MN2(p14) MN2(p15)
            MN2(p16) MN2(p17) MN2(p18) MN2(p19) MN2(p20) MN2(p21) MN2(p22) MN2(p23)
            MN2(p24) MN2(p25) MN2(p26) MN2(p27) MN2(p28) MN2(p29) MN2(p30) MN2(p31)
            #undef MN2
            if (__all(mn >= tgt)) break;
            if (++fails > 8) fast = false;   // sticky escalation to durable path
        }

        // ---- MFMA (swapped): A = W regs, B = h frags from slot pairs ----
        f32x4 aR = (f32x4){0.f,0.f,0.f,0.f};
        f32x4 aZ = (f32x4){0.f,0.f,0.f,0.f};
        f32x4 aN = (f32x4){0.f,0.f,0.f,0.f};
        #define STEP_KC(kc, A_, B_) { \
            u32x4 fw = (u32x4){A_[0], A_[2], B_[0], B_[2]}; \
            bf8_t hb = __builtin_bit_cast(bf8_t, fw); \
            aR = __builtin_amdgcn_mfma_f32_16x16x32_bf16(w[0][kc], hb, aR, 0, 0, 0); \
            aZ = __builtin_amdgcn_mfma_f32_16x16x32_bf16(w[1][kc], hb, aZ, 0, 0, 0); \
            aN = __builtin_amdgcn_mfma_f32_16x16x32_bf16(w[2][kc], hb, aN, 0, 0, 0); }
        STEP_KC(0,  p0,  p1)  STEP_KC(1,  p2,  p3)  STEP_KC(2,  p4,  p5)  STEP_KC(3,  p6,  p7)
        STEP_KC(4,  p8,  p9)  STEP_KC(5,  p10, p11) STEP_KC(6,  p12, p13) STEP_KC(7,  p14, p15)
        STEP_KC(8,  p16, p17) STEP_KC(9,  p18, p19) STEP_KC(10, p20, p21) STEP_KC(11, p22, p23)
        STEP_KC(12, p24, p25) STEP_KC(13, p26, p27) STEP_KC(14, p28, p29) STEP_KC(15, p30, p31)
        #undef STEP_KC

        // ---- gates: lane (q,cc) -> batch bgl, units u0+q*4+rg ----
        float hh[4];
        #pragma unroll
        for (int rg = 0; rg < 4; rg++) {
            float r = sigm(xr[rg] + aR[rg] + brv[rg]);
            float z = sigm(xz[rg] + aZ[rg] + bzv[rg]);
            float n = tanhs(xn[rg] + r * (aN[rg] + bnv[rg]));
            hh[rg] = (1.f - z) * n + z * hp[rg];
        }
        hp = (f32x4){hh[0], hh[1], hh[2], hh[3]};

        // ---- dual-store self-certifying slot (parity (s+1)&1, stamp s+1) ----
        u32 w0 = (u32)f2b(hh[0]) | ((u32)f2b(hh[1]) << 16);
        u32 w1 = (u32)f2b(hh[2]) | ((u32)f2b(hh[3]) << 16);
        u32x4 sv = (u32x4){w0, st1, w1, st1};
        char* ps = slotbase + (long)(((d * 2 + ((s + 1) & 1)) * 4 + bg) * 32768) + off_wr;
        asm volatile("global_store_dwordx4 %0, %1, off sc0"
                     :: "v"(ps), "v"(sv) : "memory");        // fast copy (local L2)
        asm volatile("global_store_dwordx4 %0, %1, off sc0 sc1"
                     :: "v"(ps), "v"(sv) : "memory");        // durable copy (MALL)

        if (writeX1) {
            u32x2 xv = (u32x2){w0, w1};   // 4 consecutive units at batch bgl
            *(u32x2*)(x1out + ((long)bgl * T + time) * 1024 + d * H + u0 + q * 4) = xv;
        }
        // NO drain, NO flag: next step's bulk verify certifies visibility.
    }

    // spill fp32 carry for next chunk dispatch / k_fc (kernel-boundary coherence)
    *(f32x4*)(h32d + (long)bgl * H + u0 + q * 4) = hp;
}
#undef BULK

// ------------------------------------------------------- final FC (fp32)
__global__ __launch_bounds__(256)
void k_fc(const float* __restrict__ h32, const float* __restrict__ fcw,
          const float* __restrict__ fcb, float* __restrict__ out) {
    int b   = blockIdx.x;
    int tid = threadIdx.x;
    float p[10];
    #pragma unroll
    for (int o = 0; o < 10; o++) p[o] = 0.f;
    for (int k = tid; k < 1024; k += 256) {
        int dd = k >> 9, kk = k & 511;
        float hv = h32[(long)dd * B * H + (long)b * H + kk];
        #pragma unroll
        for (int o = 0; o < 10; o++) p[o] += hv * fcw[o * 1024 + k];
    }
    __shared__ float red[10][256];
    #pragma unroll
    for (int o = 0; o < 10; o++) red[o][tid] = p[o];
    __syncthreads();
    for (int off = 128; off > 0; off >>= 1) {
        if (tid < off)
            #pragma unroll
            for (int o = 0; o < 10; o++) red[o][tid] += red[o][tid + off];
        __syncthreads();
    }
    if (tid < 10) out[b * 10 + tid] = red[tid][0] + fcb[tid];
}

// ------------------------------------------------------- launcher
extern "C" void kernel_launch(void* const* d_in, const int* in_sizes, int n_in,
                              void* d_out, int out_size, void* d_ws, size_t ws_size,
                              hipStream_t stream) {
    const int*   sent = (const int*)d_in[0];
    const float* emb  = (const float*)d_in[1];
    const float* wih0 = (const float*)d_in[2];
    const float* whh0 = (const float*)d_in[3];
    const float* bih0 = (const float*)d_in[4];
    const float* bhh0 = (const float*)d_in[5];
    const float* wih1 = (const float*)d_in[6];
    const float* whh1 = (const float*)d_in[7];
    const float* bih1 = (const float*)d_in[8];
    const float* bhh1 = (const float*)d_in[9];
    const float* fcw  = (const float*)d_in[10];
    const float* fcb  = (const float*)d_in[11];
    float* outp = (float*)d_out;

    // workspace layout — ~132.4 MB (proven-safe envelope: >=134.5 MB)
    char*  ws  = (char*)d_ws;
    float* xg  = (float*)(ws);                           // 2*CT*G3*B*4 = 50,331,648 B
    u16*   x1  = (u16*)(ws + 50331648L);                 // B*T*1024*2  = 67,108,864 B
    float* h32 = (float*)(ws + 50331648L + 67108864L);   // 2*B*H*4     =    262,144 B
    u32*   slt = (u32*)(ws + 50331648L + 67108864L + 262144L);   // slots 524,288 B
    u16*   wbf = (u16*)(ws + 50331648L + 67108864L + 262144L + 524288L);
    u16* wih0b = wbf;                      // 2*1536*256  =   786,432 el
    u16* wih1b = wbf + 786432L;            // 2*1536*1024 = 3,145,728 el
    u16* whh0b = wbf + 786432L + 3145728L; // 2*1536*512  = 1,572,864 el
    u16* whh1b = whh0b + 1572864L;         // 1,572,864 el

    // fused weight convert + layer-0 init (1 launch instead of 5)
    k_prep<<<512, 256, 0, stream>>>(wih0, wih1, whh0, whh1,
                                    wih0b, wih1b, whh0b, whh1b, h32, slt);

    dim3 gg(32, 12, 2);      // GEMM: 32 m-blocks x 12 n-tiles x 2 dirs
    // recurrence: 1-D grid of 256 so dom = bid&7 groups each domain on one XCD

    // ---- layer 0 (embedding gather fused into GEMM A-staging) ----
    for (int c = 0; c < T / CT; c++) {
        k_gemm_xg<<<gg, 256, 0, stream>>>(sent, emb, 1, wih0b, bih0, xg, E, c);
        k_chunk<<<256, 64, 0, stream>>>(whh0b, bhh0, xg, h32, slt, c, x1, 1);
    }

    // ---- layer 1 (A = x1, already bf16) ----
    k_init<<<512, 256, 0, stream>>>(h32, slt);
    for (int c = 0; c < T / CT; c++) {
        k_gemm_xg<<<gg, 256, 0, stream>>>(sent, x1, 0, wih1b, bih1, xg, 2 * H, c);
        k_chunk<<<256, 64, 0, stream>>>(whh1b, bhh1, xg, h32, slt, c, (u16*)nullptr, 0);
    }

    k_fc<<<B, 256, 0, stream>>>(h32, fcw, fcb, outp);
}

// Round 15
// 2989.545 us; speedup vs baseline: 1.0313x; 1.0313x over previous
//
#include <hip/hip_runtime.h>
#include <stdint.h>

#define H   512
#define B   64
#define T   512
#define E   256
#define G3  1536   // 3*H
#define CT  64     // time-chunk length (T/CT = 8 chunks)
#define NBG 4      // independent batch groups (16 batches each)
#define NUG 32     // unit blocks per direction (16 units each)

typedef short s16;
typedef unsigned short u16;
typedef unsigned int u32;
typedef __attribute__((ext_vector_type(8))) short   short8;
typedef __attribute__((ext_vector_type(4))) float   f32x4;
typedef __attribute__((ext_vector_type(4))) unsigned int u32x4;
typedef __attribute__((ext_vector_type(2))) unsigned int u32x2;
typedef __bf16 bf8_t __attribute__((ext_vector_type(8)));

__device__ __forceinline__ u16 f2b(float f) {
    union { float f; unsigned int i; } v; v.f = f;
    unsigned int r = v.i + 0x7FFF + ((v.i >> 16) & 1);
    return (u16)(r >> 16);
}
__device__ __forceinline__ float sigm(float x)  { return 1.f / (1.f + __expf(-x)); }
__device__ __forceinline__ float tanhs(float x) { return 1.f - 2.f / (1.f + __expf(2.f * x)); }

// ------------------------------------------------------- fused prep: weight cvt + layer-0 init
__global__ void k_prep(const float* __restrict__ wih0, const float* __restrict__ wih1,
                       const float* __restrict__ whh0, const float* __restrict__ whh1,
                       u16* __restrict__ wih0b, u16* __restrict__ wih1b,
                       u16* __restrict__ whh0b, u16* __restrict__ whh1b,
                       float* __restrict__ h32, u32* __restrict__ slots) {
    long i = (long)blockIdx.x * 256 + threadIdx.x;
    long stride = (long)gridDim.x * 256;
    for (long j = i; j < 786432L;  j += stride) wih0b[j] = f2b(wih0[j]);
    for (long j = i; j < 3145728L; j += stride) wih1b[j] = f2b(wih1[j]);
    for (long j = i; j < 1572864L; j += stride) whh0b[j] = f2b(whh0[j]);
    for (long j = i; j < 1572864L; j += stride) whh1b[j] = f2b(whh1[j]);
    for (long j = i; j < 131072L;  j += stride) slots[j] = 0;     // stamp 0 + h_0 = 0
    for (long j = i; j < 65536L;   j += stride) h32[j] = 0.f;     // fp32 carry
}

// ------------------------------------------------------- init h32/slots (between layers)
__global__ void k_init(float* __restrict__ h32, u32* __restrict__ slots) {
    int i = blockIdx.x * 256 + threadIdx.x;      // 131072 u32 = 512 KB slot buffer
    slots[i] = 0;                                 // stamp 0 + h=0 (initial state h_0)
    if (i < 65536) h32[i] = 0.f;                 // 2 dirs * B*H fp32 carry
}

// ------------------------------------------------------- xg chunk GEMM (MFMA)
// Writes xgT[d][tl][n][b] (fp32) = A[b,t,:K] . Wbf[d][n][:K] + bih[d][n]
// m-mapping: b = m&63, tl = m>>6. MFMA operands SWAPPED -> coalesced C stores.
#define BM 128
#define BN 128
#define BK 32

__global__ __launch_bounds__(256)
void k_gemm_xg(const int* __restrict__ sent, const void* __restrict__ Abuf, int aIsF32,
               const u16* __restrict__ Wbf, const float* __restrict__ bih,
               float* __restrict__ xgT, int K, int c) {
    int d  = blockIdx.z;
    int t0 = d ? (T - (c + 1) * CT) : c * CT;
    const u16* Bw = Wbf + (long)d * G3 * K;
    const float* bias = bih + (long)d * G3;
    float* C = xgT + (long)d * (long)CT * G3 * B;

    __shared__ __align__(16) s16 lA[BM * BK];
    __shared__ __align__(16) s16 lB[BN * BK];

    int tid  = threadIdx.x;
    int lane = tid & 63;
    int wv   = tid >> 6;
    int wm   = wv >> 1, wn = wv & 1;
    int q    = lane >> 4, r16 = lane & 15;

    long m0 = (long)blockIdx.x * BM;
    long n0 = (long)blockIdx.y * BN;

    const float* rowAf[2];
    const s16*   rowAh[2];
    const u16*   rowB[2];
    #pragma unroll
    for (int i = 0; i < 2; i++) {
        int ch = tid + i * 256;
        int r  = ch >> 2, cc = (ch & 3) * 8;
        long m = m0 + r;
        int  bb_ = (int)(m & 63), tl = (int)(m >> 6);   // m = (tl<<6)|b
        int  t  = t0 + tl;
        if (aIsF32) rowAf[i] = (const float*)Abuf + (long)sent[bb_ * T + t] * K + cc;
        else        rowAh[i] = (const s16*)Abuf + ((long)bb_ * T + t) * K + cc;
        rowB[i] = Bw + (n0 + r) * K + cc;
    }

    f32x4 acc[4][4];
    #pragma unroll
    for (int i = 0; i < 4; i++)
        #pragma unroll
        for (int j = 0; j < 4; j++) acc[i][j] = (f32x4){0.f, 0.f, 0.f, 0.f};

    for (long k0 = 0; k0 < K; k0 += BK) {
        #pragma unroll
        for (int i = 0; i < 2; i++) {
            if (aIsF32) {
                float4 v0 = *(const float4*)(rowAf[i] + k0);
                float4 v1 = *(const float4*)(rowAf[i] + k0 + 4);
                short8 pk;
                pk[0] = (s16)f2b(v0.x); pk[1] = (s16)f2b(v0.y);
                pk[2] = (s16)f2b(v0.z); pk[3] = (s16)f2b(v0.w);
                pk[4] = (s16)f2b(v1.x); pk[5] = (s16)f2b(v1.y);
                pk[6] = (s16)f2b(v1.z); pk[7] = (s16)f2b(v1.w);
                ((short8*)lA)[tid + i * 256] = pk;
            } else {
                ((short8*)lA)[tid + i * 256] = *(const short8*)(rowAh[i] + k0);
            }
            ((short8*)lB)[tid + i * 256] = *(const short8*)((const s16*)rowB[i] + k0);
        }
        __syncthreads();

        bf8_t af[4], bf[4];
        #pragma unroll
        for (int mt = 0; mt < 4; mt++)
            af[mt] = ((const bf8_t*)lA)[(wm * 64 + mt * 16 + r16) * 4 + q];
        #pragma unroll
        for (int nt = 0; nt < 4; nt++)
            bf[nt] = ((const bf8_t*)lB)[(wn * 64 + nt * 16 + r16) * 4 + q];
        #pragma unroll
        for (int mt = 0; mt < 4; mt++)
            #pragma unroll
            for (int nt = 0; nt < 4; nt++)
                acc[mt][nt] = __builtin_amdgcn_mfma_f32_16x16x32_bf16(
                                  bf[nt], af[mt], acc[mt][nt], 0, 0, 0);   // swapped
        __syncthreads();
    }

    // D layout (swapped): row (q*4+rg) -> n-sub, col (r16) -> m-sub
    #pragma unroll
    for (int nt = 0; nt < 4; nt++) {
        f32x4 bv = *(const f32x4*)(bias + n0 + wn * 64 + nt * 16 + q * 4);
        #pragma unroll
        for (int mt = 0; mt < 4; mt++) {
            long m = m0 + wm * 64 + mt * 16 + r16;
            long tl = m >> 6, b = m & 63;
            #pragma unroll
            for (int rg = 0; rg < 4; rg++) {
                long n = n0 + wn * 64 + nt * 16 + q * 4 + rg;
                C[(tl * G3 + n) * B + b] = acc[mt][nt][rg] + bv[rg];
            }
        }
    }
}

// bulk load macro: 32 x dwordx4, each instr 1024 lane-contiguous bytes, scope SC
#define BULK(SC) \
    asm volatile( \
        "global_load_dwordx4 %0,  %16, off " SC "\n\t" \
        "global_load_dwordx4 %1,  %16, off offset:1024 " SC "\n\t" \
        "global_load_dwordx4 %2,  %16, off offset:2048 " SC "\n\t" \
        "global_load_dwordx4 %3,  %16, off offset:3072 " SC "\n\t" \
        "global_load_dwordx4 %4,  %17, off " SC "\n\t" \
        "global_load_dwordx4 %5,  %17, off offset:1024 " SC "\n\t" \
        "global_load_dwordx4 %6,  %17, off offset:2048 " SC "\n\t" \
        "global_load_dwordx4 %7,  %17, off offset:3072 " SC "\n\t" \
        "global_load_dwordx4 %8,  %18, off " SC "\n\t" \
        "global_load_dwordx4 %9,  %18, off offset:1024 " SC "\n\t" \
        "global_load_dwordx4 %10, %18, off offset:2048 " SC "\n\t" \
        "global_load_dwordx4 %11, %18, off offset:3072 " SC "\n\t" \
        "global_load_dwordx4 %12, %19, off " SC "\n\t" \
        "global_load_dwordx4 %13, %19, off offset:1024 " SC "\n\t" \
        "global_load_dwordx4 %14, %19, off offset:2048 " SC "\n\t" \
        "global_load_dwordx4 %15, %19, off offset:3072 " SC \
        : "=&v"(p0),"=&v"(p1),"=&v"(p2),"=&v"(p3), \
          "=&v"(p4),"=&v"(p5),"=&v"(p6),"=&v"(p7), \
          "=&v"(p8),"=&v"(p9),"=&v"(p10),"=&v"(p11), \
          "=&v"(p12),"=&v"(p13),"=&v"(p14),"=&v"(p15) \
        : "v"(qa0), "v"(qa1), "v"(qa2), "v"(qa3) \
        : "memory"); \
    asm volatile( \
        "global_load_dwordx4 %0,  %16, off " SC "\n\t" \
        "global_load_dwordx4 %1,  %16, off offset:1024 " SC "\n\t" \
        "global_load_dwordx4 %2,  %16, off offset:2048 " SC "\n\t" \
        "global_load_dwordx4 %3,  %16, off offset:3072 " SC "\n\t" \
        "global_load_dwordx4 %4,  %17, off " SC "\n\t" \
        "global_load_dwordx4 %5,  %17, off offset:1024 " SC "\n\t" \
        "global_load_dwordx4 %6,  %17, off offset:2048 " SC "\n\t" \
        "global_load_dwordx4 %7,  %17, off offset:3072 " SC "\n\t" \
        "global_load_dwordx4 %8,  %18, off " SC "\n\t" \
        "global_load_dwordx4 %9,  %18, off offset:1024 " SC "\n\t" \
        "global_load_dwordx4 %10, %18, off offset:2048 " SC "\n\t" \
        "global_load_dwordx4 %11, %18, off offset:3072 " SC "\n\t" \
        "global_load_dwordx4 %12, %19, off " SC "\n\t" \
        "global_load_dwordx4 %13, %19, off offset:1024 " SC "\n\t" \
        "global_load_dwordx4 %14, %19, off offset:2048 " SC "\n\t" \
        "global_load_dwordx4 %15, %19, off offset:3072 " SC "\n\t" \
        "s_waitcnt vmcnt(0)" \
        : "=&v"(p16),"=&v"(p17),"=&v"(p18),"=&v"(p19), \
          "=&v"(p20),"=&v"(p21),"=&v"(p22),"=&v"(p23), \
          "=&v"(p24),"=&v"(p25),"=&v"(p26),"=&v"(p27), \
          "=&v"(p28),"=&v"(p29),"=&v"(p30),"=&v"(p31) \
        : "v"(qa4), "v"(qa5), "v"(qa6), "v"(qa7) \
        : "memory");

// ------------------------------------------------------- wave-autonomous chunk recurrence
// 1-D grid of 256 single-wave blocks: dom = bid&7 -> (d,bg); ug = bid>>3.
// Single-XCD domains under round-robin placement; slot traffic in local L2.
// Protocol identical to R12/R14 (dual-store sc0 + sc0 sc1; sc0 bulk verify-retry
// with sticky sc1 escalation). NEW: de-convoy sleeps —
//  (a) s_sleep(4) before each step's first bulk (skips the guaranteed-fail round
//      issued before producers' stores land);
//  (b) s_sleep(2) between failed rounds (halves spin traffic through the XCD L2
//      that producer stores must also traverse -> shorter straggler tail).
// Pure delays: no sync-semantics change, cannot hang.
__global__ __launch_bounds__(64, 1)
void k_chunk(const u16* __restrict__ Whhbf, const float* __restrict__ bhh,
             const float* __restrict__ xgT, float* __restrict__ h32,
             u32* __restrict__ slots, int c, u16* __restrict__ x1out, int writeX1) {
    int bid = blockIdx.x;
    int dom = bid & 7;                   // sync domain: one XCD under round-robin
    int ug  = bid >> 3;                  // unit group: units ug*16..+15
    int d   = dom >> 2;
    int bg  = dom & 3;
    int lane = threadIdx.x;              // 0..63
    int q = lane >> 4, cc = lane & 15;
    int u0 = ug * 16;
    int bgl = bg * 16 + cc;              // this lane's batch (D-col side)

    const u16* W    = Whhbf + (long)d * G3 * H;
    const float* bb = bhh + (long)d * G3;
    const float* xgf = xgT + (long)d * (long)CT * G3 * B;
    float* h32d = h32 + (long)d * B * H;
    char* slotbase = (char*)slots;

    // ---- weight slice as registers (A-frag) ----
    bf8_t w[3][16];
    #pragma unroll
    for (int gate = 0; gate < 3; gate++)
        #pragma unroll
        for (int kc = 0; kc < 16; kc++)
            w[gate][kc] = *(const bf8_t*)(W + (long)(gate * H + u0 + cc) * H + kc * 32 + q * 8);

    // per-unit biases, f32x4 over rg (units u0+q*4..+3)
    f32x4 brv = *(const f32x4*)(bb + u0 + q * 4);
    f32x4 bzv = *(const f32x4*)(bb + H + u0 + q * 4);
    f32x4 bnv = *(const f32x4*)(bb + 2 * H + u0 + q * 4);

    // fp32 h-carry: lane holds h[b=bgl][u0+q*4+rg] -> f32x4
    f32x4 hp = *(const f32x4*)(h32d + (long)bgl * H + u0 + q * 4);

    // producer slot byte offset (within a 32KB (d,parity,bg) block)
    int jw = ug * 4 + q;                 // unit quad index of this lane's 4 units
    long off_wr = (long)((jw >> 3) * 2 + (jw & 1)) * 1024
                + (long)((jw >> 1) & 3) * 256 + cc * 16;

    int base = c * CT;
    bool fast = true;                    // sticky: escalate to sc1 reads on trouble

    for (int sl = 0; sl < CT; sl++) {
        int s    = base + sl;
        int tl   = d ? (CT - 1 - sl) : sl;
        int time = d ? (T - 1 - s) : s;
        int tgt  = s;
        u32 st1  = (u32)(s + 1);

        // xg loads: issued first; latency hidden under the pre-poll sleep + bulk.
        const float* xgb = xgf + ((long)tl * G3 + u0 + q * 4) * B + bgl;
        float xr[4], xz[4], xn[4];
        #pragma unroll
        for (int jj = 0; jj < 4; jj++) {
            xr[jj] = xgb[(long)jj * B];
            xz[jj] = xgb[(long)H * B + (long)jj * B];
            xn[jj] = xgb[(long)2 * H * B + (long)jj * B];
        }

        const char* domb = slotbase + (long)(((d * 2 + (s & 1)) * 4 + bg) * 32768);
        const char* pb  = domb + lane * 16;
        const char* qa0 = pb;
        const char* qa1 = pb + 4096;
        const char* qa2 = pb + 8192;
        const char* qa3 = pb + 12288;
        const char* qa4 = pb + 16384;
        const char* qa5 = pb + 20480;
        const char* qa6 = pb + 24576;
        const char* qa7 = pb + 28672;
        u32x4 p0,p1,p2,p3,p4,p5,p6,p7,p8,p9,p10,p11,p12,p13,p14,p15;
        u32x4 p16,p17,p18,p19,p20,p21,p22,p23,p24,p25,p26,p27,p28,p29,p30,p31;

        if (sl > 0) __builtin_amdgcn_s_sleep(4);   // (a) skip the guaranteed-fail round
        int fails = 0;
        for (;;) {
            // ---- fused bulk load + full stamp verify (retry on straggler) ----
            if (fast) { BULK("sc0") }
            else      { BULK("sc0 sc1") }
            __builtin_amdgcn_sched_barrier(0);   // stamp checks must not hoist above vmcnt
            int mn = min((int)p0[1], (int)p0[3]);
            #define MN2(x) mn = min(mn, min((int)x[1], (int)x[3]));
            MN2(p1)  MN2(p2)  MN2(p3)  MN2(p4)  MN2(p5)  MN2(p6)  MN2(p7)
            MN2(p8)  MN2(p9)  MN2(p10) MN2(p11) MN2(p12) MN2(p13) MN2(p14) MN2(p15)
            MN2(p16) MN2(p17) MN2(p18) MN2(p19) MN2(p20) MN2(p21) MN2(p22) MN2(p23)
            MN2(p24) MN2(p25) MN2(p26) MN2(p27) MN2(p28) MN2(p29) MN2(p30) MN2(p31)
            #undef MN2
            if (__all(mn >= tgt)) break;
            if (++fails > 8) fast = false;   // sticky escalation to durable path
            __builtin_amdgcn_s_sleep(2);     // (b) backoff: cut spin traffic
        }

        // ---- MFMA (swapped): A = W regs, B = h frags from slot pairs ----
        f32x4 aR = (f32x4){0.f,0.f,0.f,0.f};
        f32x4 aZ = (f32x4){0.f,0.f,0.f,0.f};
        f32x4 aN = (f32x4){0.f,0.f,0.f,0.f};
        #define STEP_KC(kc, A_, B_) { \
            u32x4 fw = (u32x4){A_[0], A_[2], B_[0], B_[2]}; \
            bf8_t hb = __builtin_bit_cast(bf8_t, fw); \
            aR = __builtin_amdgcn_mfma_f32_16x16x32_bf16(w[0][kc], hb, aR, 0, 0, 0); \
            aZ = __builtin_amdgcn_mfma_f32_16x16x32_bf16(w[1][kc], hb, aZ, 0, 0, 0); \
            aN = __builtin_amdgcn_mfma_f32_16x16x32_bf16(w[2][kc], hb, aN, 0, 0, 0); }
        STEP_KC(0,  p0,  p1)  STEP_KC(1,  p2,  p3)  STEP_KC(2,  p4,  p5)  STEP_KC(3,  p6,  p7)
        STEP_KC(4,  p8,  p9)  STEP_KC(5,  p10, p11) STEP_KC(6,  p12, p13) STEP_KC(7,  p14, p15)
        STEP_KC(8,  p16, p17) STEP_KC(9,  p18, p19) STEP_KC(10, p20, p21) STEP_KC(11, p22, p23)
        STEP_KC(12, p24, p25) STEP_KC(13, p26, p27) STEP_KC(14, p28, p29) STEP_KC(15, p30, p31)
        #undef STEP_KC

        // ---- gates: lane (q,cc) -> batch bgl, units u0+q*4+rg ----
        float hh[4];
        #pragma unroll
        for (int rg = 0; rg < 4; rg++) {
            float r = sigm(xr[rg] + aR[rg] + brv[rg]);
            float z = sigm(xz[rg] + aZ[rg] + bzv[rg]);
            float n = tanhs(xn[rg] + r * (aN[rg] + bnv[rg]));
            hh[rg] = (1.f - z) * n + z * hp[rg];
        }
        hp = (f32x4){hh[0], hh[1], hh[2], hh[3]};

        // ---- dual-store self-certifying slot (parity (s+1)&1, stamp s+1) ----
        u32 w0 = (u32)f2b(hh[0]) | ((u32)f2b(hh[1]) << 16);
        u32 w1 = (u32)f2b(hh[2]) | ((u32)f2b(hh[3]) << 16);
        u32x4 sv = (u32x4){w0, st1, w1, st1};
        char* ps = slotbase + (long)(((d * 2 + ((s + 1) & 1)) * 4 + bg) * 32768) + off_wr;
        asm volatile("global_store_dwordx4 %0, %1, off sc0"
                     :: "v"(ps), "v"(sv) : "memory");        // fast copy (local L2)
        asm volatile("global_store_dwordx4 %0, %1, off sc0 sc1"
                     :: "v"(ps), "v"(sv) : "memory");        // durable copy (MALL)

        if (writeX1) {
            u32x2 xv = (u32x2){w0, w1};   // 4 consecutive units at batch bgl
            *(u32x2*)(x1out + ((long)bgl * T + time) * 1024 + d * H + u0 + q * 4) = xv;
        }
        // NO drain, NO flag: next step's bulk verify certifies visibility.
    }

    // spill fp32 carry for next chunk dispatch / k_fc (kernel-boundary coherence)
    *(f32x4*)(h32d + (long)bgl * H + u0 + q * 4) = hp;
}
#undef BULK

// ------------------------------------------------------- final FC (fp32)
__global__ __launch_bounds__(256)
void k_fc(const float* __restrict__ h32, const float* __restrict__ fcw,
          const float* __restrict__ fcb, float* __restrict__ out) {
    int b   = blockIdx.x;
    int tid = threadIdx.x;
    float p[10];
    #pragma unroll
    for (int o = 0; o < 10; o++) p[o] = 0.f;
    for (int k = tid; k < 1024; k += 256) {
        int dd = k >> 9, kk = k & 511;
        float hv = h32[(long)dd * B * H + (long)b * H + kk];
        #pragma unroll
        for (int o = 0; o < 10; o++) p[o] += hv * fcw[o * 1024 + k];
    }
    __shared__ float red[10][256];
    #pragma unroll
    for (int o = 0; o < 10; o++) red[o][tid] = p[o];
    __syncthreads();
    for (int off = 128; off > 0; off >>= 1) {
        if (tid < off)
            #pragma unroll
            for (int o = 0; o < 10; o++) red[o][tid] += red[o][tid + off];
        __syncthreads();
    }
    if (tid < 10) out[b * 10 + tid] = red[tid][0] + fcb[tid];
}

// ------------------------------------------------------- launcher
extern "C" void kernel_launch(void* const* d_in, const int* in_sizes, int n_in,
                              void* d_out, int out_size, void* d_ws, size_t ws_size,
                              hipStream_t stream) {
    const int*   sent = (const int*)d_in[0];
    const float* emb  = (const float*)d_in[1];
    const float* wih0 = (const float*)d_in[2];
    const float* whh0 = (const float*)d_in[3];
    const float* bih0 = (const float*)d_in[4];
    const float* bhh0 = (const float*)d_in[5];
    const float* wih1 = (const float*)d_in[6];
    const float* whh1 = (const float*)d_in[7];
    const float* bih1 = (const float*)d_in[8];
    const float* bhh1 = (const float*)d_in[9];
    const float* fcw  = (const float*)d_in[10];
    const float* fcb  = (const float*)d_in[11];
    float* outp = (float*)d_out;

    // workspace layout — ~132.4 MB (proven-safe envelope: >=134.5 MB)
    char*  ws  = (char*)d_ws;
    float* xg  = (float*)(ws);                           // 2*CT*G3*B*4 = 50,331,648 B
    u16*   x1  = (u16*)(ws + 50331648L);                 // B*T*1024*2  = 67,108,864 B
    float* h32 = (float*)(ws + 50331648L + 67108864L);   // 2*B*H*4     =    262,144 B
    u32*   slt = (u32*)(ws + 50331648L + 67108864L + 262144L);   // slots 524,288 B
    u16*   wbf = (u16*)(ws + 50331648L + 67108864L + 262144L + 524288L);
    u16* wih0b = wbf;                      // 2*1536*256  =   786,432 el
    u16* wih1b = wbf + 786432L;            // 2*1536*1024 = 3,145,728 el
    u16* whh0b = wbf + 786432L + 3145728L; // 2*1536*512  = 1,572,864 el
    u16* whh1b = whh0b + 1572864L;         // 1,572,864 el

    // fused weight convert + layer-0 init (1 launch instead of 5)
    k_prep<<<512, 256, 0, stream>>>(wih0, wih1, whh0, whh1,
                                    wih0b, wih1b, whh0b, whh1b, h32, slt);

    dim3 gg(32, 12, 2);      // GEMM: 32 m-blocks x 12 n-tiles x 2 dirs
    // recurrence: 1-D grid of 256 so dom = bid&7 groups each domain on one XCD

    // ---- layer 0 (embedding gather fused into GEMM A-staging) ----
    for (int c = 0; c < T / CT; c++) {
        k_gemm_xg<<<gg, 256, 0, stream>>>(sent, emb, 1, wih0b, bih0, xg, E, c);
        k_chunk<<<256, 64, 0, stream>>>(whh0b, bhh0, xg, h32, slt, c, x1, 1);
    }

    // ---- layer 1 (A = x1, already bf16) ----
    k_init<<<512, 256, 0, stream>>>(h32, slt);
    for (int c = 0; c < T / CT; c++) {
        k_gemm_xg<<<gg, 256, 0, stream>>>(sent, x1, 0, wih1b, bih1, xg, 2 * H, c);
        k_chunk<<<256, 64, 0, stream>>>(whh1b, bhh1, xg, h32, slt, c, (u16*)nullptr, 0);
    }

    k_fc<<<B, 256, 0, stream>>>(h32, fcw, fcb, outp);
}

// Round 16
// 2893.034 us; speedup vs baseline: 1.0657x; 1.0334x over previous
//
#include <hip/hip_runtime.h>
#include <stdint.h>

#define H   512
#define B   64
#define T   512
#define E   256
#define G3  1536   // 3*H
#define CT  64     // time-chunk length (T/CT = 8 chunks)
#define NBG 4      // independent batch groups (16 batches each)
#define NUG 32     // unit blocks per direction (16 units each)

typedef short s16;
typedef unsigned short u16;
typedef unsigned int u32;
typedef __attribute__((ext_vector_type(8))) short   short8;
typedef __attribute__((ext_vector_type(4))) float   f32x4;
typedef __attribute__((ext_vector_type(4))) unsigned int u32x4;
typedef __attribute__((ext_vector_type(2))) unsigned int u32x2;
typedef __bf16 bf8_t __attribute__((ext_vector_type(8)));

__device__ __forceinline__ u16 f2b(float f) {
    union { float f; unsigned int i; } v; v.f = f;
    unsigned int r = v.i + 0x7FFF + ((v.i >> 16) & 1);
    return (u16)(r >> 16);
}
__device__ __forceinline__ float sigm(float x)  { return 1.f / (1.f + __expf(-x)); }
__device__ __forceinline__ float tanhs(float x) { return 1.f - 2.f / (1.f + __expf(2.f * x)); }

// ------------------------------------------------------- fused prep: weight cvt + layer-0 init
__global__ void k_prep(const float* __restrict__ wih0, const float* __restrict__ wih1,
                       const float* __restrict__ whh0, const float* __restrict__ whh1,
                       u16* __restrict__ wih0b, u16* __restrict__ wih1b,
                       u16* __restrict__ whh0b, u16* __restrict__ whh1b,
                       float* __restrict__ h32, u32* __restrict__ slots) {
    long i = (long)blockIdx.x * 256 + threadIdx.x;
    long stride = (long)gridDim.x * 256;
    for (long j = i; j < 786432L;  j += stride) wih0b[j] = f2b(wih0[j]);
    for (long j = i; j < 3145728L; j += stride) wih1b[j] = f2b(wih1[j]);
    for (long j = i; j < 1572864L; j += stride) whh0b[j] = f2b(whh0[j]);
    for (long j = i; j < 1572864L; j += stride) whh1b[j] = f2b(whh1[j]);
    for (long j = i; j < 131072L;  j += stride) slots[j] = 0;     // stamp 0 + h_0 = 0
    for (long j = i; j < 65536L;   j += stride) h32[j] = 0.f;     // fp32 carry
}

// ------------------------------------------------------- init h32/slots (between layers)
__global__ void k_init(float* __restrict__ h32, u32* __restrict__ slots) {
    int i = blockIdx.x * 256 + threadIdx.x;      // 131072 u32 = 512 KB slot buffer
    slots[i] = 0;                                 // stamp 0 + h=0 (initial state h_0)
    if (i < 65536) h32[i] = 0.f;                 // 2 dirs * B*H fp32 carry
}

// ------------------------------------------------------- xg chunk GEMM (MFMA)
// Writes xgT[d][tl][n][b] (fp32) = A[b,t,:K] . Wbf[d][n][:K] + bih[d][n]
// m-mapping: b = m&63, tl = m>>6. MFMA operands SWAPPED -> coalesced C stores.
#define BM 128
#define BN 128
#define BK 32

__global__ __launch_bounds__(256)
void k_gemm_xg(const int* __restrict__ sent, const void* __restrict__ Abuf, int aIsF32,
               const u16* __restrict__ Wbf, const float* __restrict__ bih,
               float* __restrict__ xgT, int K, int c) {
    int d  = blockIdx.z;
    int t0 = d ? (T - (c + 1) * CT) : c * CT;
    const u16* Bw = Wbf + (long)d * G3 * K;
    const float* bias = bih + (long)d * G3;
    float* C = xgT + (long)d * (long)CT * G3 * B;

    __shared__ __align__(16) s16 lA[BM * BK];
    __shared__ __align__(16) s16 lB[BN * BK];

    int tid  = threadIdx.x;
    int lane = tid & 63;
    int wv   = tid >> 6;
    int wm   = wv >> 1, wn = wv & 1;
    int q    = lane >> 4, r16 = lane & 15;

    long m0 = (long)blockIdx.x * BM;
    long n0 = (long)blockIdx.y * BN;

    const float* rowAf[2];
    const s16*   rowAh[2];
    const u16*   rowB[2];
    #pragma unroll
    for (int i = 0; i < 2; i++) {
        int ch = tid + i * 256;
        int r  = ch >> 2, cc = (ch & 3) * 8;
        long m = m0 + r;
        int  bb_ = (int)(m & 63), tl = (int)(m >> 6);   // m = (tl<<6)|b
        int  t  = t0 + tl;
        if (aIsF32) rowAf[i] = (const float*)Abuf + (long)sent[bb_ * T + t] * K + cc;
        else        rowAh[i] = (const s16*)Abuf + ((long)bb_ * T + t) * K + cc;
        rowB[i] = Bw + (n0 + r) * K + cc;
    }

    f32x4 acc[4][4];
    #pragma unroll
    for (int i = 0; i < 4; i++)
        #pragma unroll
        for (int j = 0; j < 4; j++) acc[i][j] = (f32x4){0.f, 0.f, 0.f, 0.f};

    for (long k0 = 0; k0 < K; k0 += BK) {
        #pragma unroll
        for (int i = 0; i < 2; i++) {
            if (aIsF32) {
                float4 v0 = *(const float4*)(rowAf[i] + k0);
                float4 v1 = *(const float4*)(rowAf[i] + k0 + 4);
                short8 pk;
                pk[0] = (s16)f2b(v0.x); pk[1] = (s16)f2b(v0.y);
                pk[2] = (s16)f2b(v0.z); pk[3] = (s16)f2b(v0.w);
                pk[4] = (s16)f2b(v1.x); pk[5] = (s16)f2b(v1.y);
                pk[6] = (s16)f2b(v1.z); pk[7] = (s16)f2b(v1.w);
                ((short8*)lA)[tid + i * 256] = pk;
            } else {
                ((short8*)lA)[tid + i * 256] = *(const short8*)(rowAh[i] + k0);
            }
            ((short8*)lB)[tid + i * 256] = *(const short8*)((const s16*)rowB[i] + k0);
        }
        __syncthreads();

        bf8_t af[4], bf[4];
        #pragma unroll
        for (int mt = 0; mt < 4; mt++)
            af[mt] = ((const bf8_t*)lA)[(wm * 64 + mt * 16 + r16) * 4 + q];
        #pragma unroll
        for (int nt = 0; nt < 4; nt++)
            bf[nt] = ((const bf8_t*)lB)[(wn * 64 + nt * 16 + r16) * 4 + q];
        #pragma unroll
        for (int mt = 0; mt < 4; mt++)
            #pragma unroll
            for (int nt = 0; nt < 4; nt++)
                acc[mt][nt] = __builtin_amdgcn_mfma_f32_16x16x32_bf16(
                                  bf[nt], af[mt], acc[mt][nt], 0, 0, 0);   // swapped
        __syncthreads();
    }

    // D layout (swapped): row (q*4+rg) -> n-sub, col (r16) -> m-sub
    #pragma unroll
    for (int nt = 0; nt < 4; nt++) {
        f32x4 bv = *(const f32x4*)(bias + n0 + wn * 64 + nt * 16 + q * 4);
        #pragma unroll
        for (int mt = 0; mt < 4; mt++) {
            long m = m0 + wm * 64 + mt * 16 + r16;
            long tl = m >> 6, b = m & 63;
            #pragma unroll
            for (int rg = 0; rg < 4; rg++) {
                long n = n0 + wn * 64 + nt * 16 + q * 4 + rg;
                C[(tl * G3 + n) * B + b] = acc[mt][nt][rg] + bv[rg];
            }
        }
    }
}

// bulk load macro: 32 x dwordx4, each instr 1024 lane-contiguous bytes, scope SC
#define BULK(SC) \
    asm volatile( \
        "global_load_dwordx4 %0,  %16, off " SC "\n\t" \
        "global_load_dwordx4 %1,  %16, off offset:1024 " SC "\n\t" \
        "global_load_dwordx4 %2,  %16, off offset:2048 " SC "\n\t" \
        "global_load_dwordx4 %3,  %16, off offset:3072 " SC "\n\t" \
        "global_load_dwordx4 %4,  %17, off " SC "\n\t" \
        "global_load_dwordx4 %5,  %17, off offset:1024 " SC "\n\t" \
        "global_load_dwordx4 %6,  %17, off offset:2048 " SC "\n\t" \
        "global_load_dwordx4 %7,  %17, off offset:3072 " SC "\n\t" \
        "global_load_dwordx4 %8,  %18, off " SC "\n\t" \
        "global_load_dwordx4 %9,  %18, off offset:1024 " SC "\n\t" \
        "global_load_dwordx4 %10, %18, off offset:2048 " SC "\n\t" \
        "global_load_dwordx4 %11, %18, off offset:3072 " SC "\n\t" \
        "global_load_dwordx4 %12, %19, off " SC "\n\t" \
        "global_load_dwordx4 %13, %19, off offset:1024 " SC "\n\t" \
        "global_load_dwordx4 %14, %19, off offset:2048 " SC "\n\t" \
        "global_load_dwordx4 %15, %19, off offset:3072 " SC \
        : "=&v"(p0),"=&v"(p1),"=&v"(p2),"=&v"(p3), \
          "=&v"(p4),"=&v"(p5),"=&v"(p6),"=&v"(p7), \
          "=&v"(p8),"=&v"(p9),"=&v"(p10),"=&v"(p11), \
          "=&v"(p12),"=&v"(p13),"=&v"(p14),"=&v"(p15) \
        : "v"(qa0), "v"(qa1), "v"(qa2), "v"(qa3) \
        : "memory"); \
    asm volatile( \
        "global_load_dwordx4 %0,  %16, off " SC "\n\t" \
        "global_load_dwordx4 %1,  %16, off offset:1024 " SC "\n\t" \
        "global_load_dwordx4 %2,  %16, off offset:2048 " SC "\n\t" \
        "global_load_dwordx4 %3,  %16, off offset:3072 " SC "\n\t" \
        "global_load_dwordx4 %4,  %17, off " SC "\n\t" \
        "global_load_dwordx4 %5,  %17, off offset:1024 " SC "\n\t" \
        "global_load_dwordx4 %6,  %17, off offset:2048 " SC "\n\t" \
        "global_load_dwordx4 %7,  %17, off offset:3072 " SC "\n\t" \
        "global_load_dwordx4 %8,  %18, off " SC "\n\t" \
        "global_load_dwordx4 %9,  %18, off offset:1024 " SC "\n\t" \
        "global_load_dwordx4 %10, %18, off offset:2048 " SC "\n\t" \
        "global_load_dwordx4 %11, %18, off offset:3072 " SC "\n\t" \
        "global_load_dwordx4 %12, %19, off " SC "\n\t" \
        "global_load_dwordx4 %13, %19, off offset:1024 " SC "\n\t" \
        "global_load_dwordx4 %14, %19, off offset:2048 " SC "\n\t" \
        "global_load_dwordx4 %15, %19, off offset:3072 " SC "\n\t" \
        "s_waitcnt vmcnt(0)" \
        : "=&v"(p16),"=&v"(p17),"=&v"(p18),"=&v"(p19), \
          "=&v"(p20),"=&v"(p21),"=&v"(p22),"=&v"(p23), \
          "=&v"(p24),"=&v"(p25),"=&v"(p26),"=&v"(p27), \
          "=&v"(p28),"=&v"(p29),"=&v"(p30),"=&v"(p31) \
        : "v"(qa4), "v"(qa5), "v"(qa6), "v"(qa7) \
        : "memory");

// ------------------------------------------------------- wave-autonomous chunk recurrence
// 1-D grid of 256 single-wave blocks: dom = bid&7 -> (d,bg); ug = bid>>3.
// Single-XCD domains under round-robin placement; slot traffic in local L2.
// Protocol identical to R12/R14/R15 (dual-store sc0 + sc0 sc1; sc0 bulk
// verify-retry with sticky sc1 escalation). Calibrated de-convoy sleeps:
//  (a) s_sleep(8) pre-poll (~0.21us) — cover the producer store-landing window
//      so the first bulk verifies on the first try;
//  (b) s_sleep(4) backoff between failed rounds — yield the L2 to in-flight
//      producer stores (shorter straggler tail).
// Pure delays: no sync-semantics change, cannot hang.
__global__ __launch_bounds__(64, 1)
void k_chunk(const u16* __restrict__ Whhbf, const float* __restrict__ bhh,
             const float* __restrict__ xgT, float* __restrict__ h32,
             u32* __restrict__ slots, int c, u16* __restrict__ x1out, int writeX1) {
    int bid = blockIdx.x;
    int dom = bid & 7;                   // sync domain: one XCD under round-robin
    int ug  = bid >> 3;                  // unit group: units ug*16..+15
    int d   = dom >> 2;
    int bg  = dom & 3;
    int lane = threadIdx.x;              // 0..63
    int q = lane >> 4, cc = lane & 15;
    int u0 = ug * 16;
    int bgl = bg * 16 + cc;              // this lane's batch (D-col side)

    const u16* W    = Whhbf + (long)d * G3 * H;
    const float* bb = bhh + (long)d * G3;
    const float* xgf = xgT + (long)d * (long)CT * G3 * B;
    float* h32d = h32 + (long)d * B * H;
    char* slotbase = (char*)slots;

    // ---- weight slice as registers (A-frag) ----
    bf8_t w[3][16];
    #pragma unroll
    for (int gate = 0; gate < 3; gate++)
        #pragma unroll
        for (int kc = 0; kc < 16; kc++)
            w[gate][kc] = *(const bf8_t*)(W + (long)(gate * H + u0 + cc) * H + kc * 32 + q * 8);

    // per-unit biases, f32x4 over rg (units u0+q*4..+3)
    f32x4 brv = *(const f32x4*)(bb + u0 + q * 4);
    f32x4 bzv = *(const f32x4*)(bb + H + u0 + q * 4);
    f32x4 bnv = *(const f32x4*)(bb + 2 * H + u0 + q * 4);

    // fp32 h-carry: lane holds h[b=bgl][u0+q*4+rg] -> f32x4
    f32x4 hp = *(const f32x4*)(h32d + (long)bgl * H + u0 + q * 4);

    // producer slot byte offset (within a 32KB (d,parity,bg) block)
    int jw = ug * 4 + q;                 // unit quad index of this lane's 4 units
    long off_wr = (long)((jw >> 3) * 2 + (jw & 1)) * 1024
                + (long)((jw >> 1) & 3) * 256 + cc * 16;

    int base = c * CT;
    bool fast = true;                    // sticky: escalate to sc1 reads on trouble

    for (int sl = 0; sl < CT; sl++) {
        int s    = base + sl;
        int tl   = d ? (CT - 1 - sl) : sl;
        int time = d ? (T - 1 - s) : s;
        int tgt  = s;
        u32 st1  = (u32)(s + 1);

        // xg loads: issued first; latency hidden under the pre-poll sleep + bulk.
        const float* xgb = xgf + ((long)tl * G3 + u0 + q * 4) * B + bgl;
        float xr[4], xz[4], xn[4];
        #pragma unroll
        for (int jj = 0; jj < 4; jj++) {
            xr[jj] = xgb[(long)jj * B];
            xz[jj] = xgb[(long)H * B + (long)jj * B];
            xn[jj] = xgb[(long)2 * H * B + (long)jj * B];
        }

        const char* domb = slotbase + (long)(((d * 2 + (s & 1)) * 4 + bg) * 32768);
        const char* pb  = domb + lane * 16;
        const char* qa0 = pb;
        const char* qa1 = pb + 4096;
        const char* qa2 = pb + 8192;
        const char* qa3 = pb + 12288;
        const char* qa4 = pb + 16384;
        const char* qa5 = pb + 20480;
        const char* qa6 = pb + 24576;
        const char* qa7 = pb + 28672;
        u32x4 p0,p1,p2,p3,p4,p5,p6,p7,p8,p9,p10,p11,p12,p13,p14,p15;
        u32x4 p16,p17,p18,p19,p20,p21,p22,p23,p24,p25,p26,p27,p28,p29,p30,p31;

        if (sl > 0) __builtin_amdgcn_s_sleep(8);   // (a) cover store-landing window
        int fails = 0;
        for (;;) {
            // ---- fused bulk load + full stamp verify (retry on straggler) ----
            if (fast) { BULK("sc0") }
            else      { BULK("sc0 sc1") }
            __builtin_amdgcn_sched_barrier(0);   // stamp checks must not hoist above vmcnt
            int mn = min((int)p0[1], (int)p0[3]);
            #define MN2(x) mn = min(mn, min((int)x[1], (int)x[3]));
            MN2(p1)  MN2(p2)  MN2(p3)  MN2(p4)  MN2(p5)  MN2(p6)  MN2(p7)
            MN2(p8)  MN2(p9)  MN2(p10) MN2(p11) MN2(p12) MN2(p13) MN2(p14) MN2(p15)
            MN2(p16) MN2(p17) MN2(p18) MN2(p19) MN2(p20) MN2(p21) MN2(p22) MN2(p23)
            MN2(p24) MN2(p25) MN2(p26) MN2(p27) MN2(p28) MN2(p29) MN2(p30) MN2(p31)
            #undef MN2
            if (__all(mn >= tgt)) break;
            if (++fails > 8) fast = false;   // sticky escalation to durable path
            __builtin_amdgcn_s_sleep(4);     // (b) backoff: yield L2 to stores
        }

        // ---- MFMA (swapped): A = W regs, B = h frags from slot pairs ----
        f32x4 aR = (f32x4){0.f,0.f,0.f,0.f};
        f32x4 aZ = (f32x4){0.f,0.f,0.f,0.f};
        f32x4 aN = (f32x4){0.f,0.f,0.f,0.f};
        #define STEP_KC(kc, A_, B_) { \
            u32x4 fw = (u32x4){A_[0], A_[2], B_[0], B_[2]}; \
            bf8_t hb = __builtin_bit_cast(bf8_t, fw); \
            aR = __builtin_amdgcn_mfma_f32_16x16x32_bf16(w[0][kc], hb, aR, 0, 0, 0); \
            aZ = __builtin_amdgcn_mfma_f32_16x16x32_bf16(w[1][kc], hb, aZ, 0, 0, 0); \
            aN = __builtin_amdgcn_mfma_f32_16x16x32_bf16(w[2][kc], hb, aN, 0, 0, 0); }
        STEP_KC(0,  p0,  p1)  STEP_KC(1,  p2,  p3)  STEP_KC(2,  p4,  p5)  STEP_KC(3,  p6,  p7)
        STEP_KC(4,  p8,  p9)  STEP_KC(5,  p10, p11) STEP_KC(6,  p12, p13) STEP_KC(7,  p14, p15)
        STEP_KC(8,  p16, p17) STEP_KC(9,  p18, p19) STEP_KC(10, p20, p21) STEP_KC(11, p22, p23)
        STEP_KC(12, p24, p25) STEP_KC(13, p26, p27) STEP_KC(14, p28, p29) STEP_KC(15, p30, p31)
        #undef STEP_KC

        // ---- gates: lane (q,cc) -> batch bgl, units u0+q*4+rg ----
        float hh[4];
        #pragma unroll
        for (int rg = 0; rg < 4; rg++) {
            float r = sigm(xr[rg] + aR[rg] + brv[rg]);
            float z = sigm(xz[rg] + aZ[rg] + bzv[rg]);
            float n = tanhs(xn[rg] + r * (aN[rg] + bnv[rg]));
            hh[rg] = (1.f - z) * n + z * hp[rg];
        }
        hp = (f32x4){hh[0], hh[1], hh[2], hh[3]};

        // ---- dual-store self-certifying slot (parity (s+1)&1, stamp s+1) ----
        u32 w0 = (u32)f2b(hh[0]) | ((u32)f2b(hh[1]) << 16);
        u32 w1 = (u32)f2b(hh[2]) | ((u32)f2b(hh[3]) << 16);
        u32x4 sv = (u32x4){w0, st1, w1, st1};
        char* ps = slotbase + (long)(((d * 2 + ((s + 1) & 1)) * 4 + bg) * 32768) + off_wr;
        asm volatile("global_store_dwordx4 %0, %1, off sc0"
                     :: "v"(ps), "v"(sv) : "memory");        // fast copy (local L2)
        asm volatile("global_store_dwordx4 %0, %1, off sc0 sc1"
                     :: "v"(ps), "v"(sv) : "memory");        // durable copy (MALL)

        if (writeX1) {
            u32x2 xv = (u32x2){w0, w1};   // 4 consecutive units at batch bgl
            *(u32x2*)(x1out + ((long)bgl * T + time) * 1024 + d * H + u0 + q * 4) = xv;
        }
        // NO drain, NO flag: next step's bulk verify certifies visibility.
    }

    // spill fp32 carry for next chunk dispatch / k_fc (kernel-boundary coherence)
    *(f32x4*)(h32d + (long)bgl * H + u0 + q * 4) = hp;
}
#undef BULK

// ------------------------------------------------------- final FC (fp32)
__global__ __launch_bounds__(256)
void k_fc(const float* __restrict__ h32, const float* __restrict__ fcw,
          const float* __restrict__ fcb, float* __restrict__ out) {
    int b   = blockIdx.x;
    int tid = threadIdx.x;
    float p[10];
    #pragma unroll
    for (int o = 0; o < 10; o++) p[o] = 0.f;
    for (int k = tid; k < 1024; k += 256) {
        int dd = k >> 9, kk = k & 511;
        float hv = h32[(long)dd * B * H + (long)b * H + kk];
        #pragma unroll
        for (int o = 0; o < 10; o++) p[o] += hv * fcw[o * 1024 + k];
    }
    __shared__ float red[10][256];
    #pragma unroll
    for (int o = 0; o < 10; o++) red[o][tid] = p[o];
    __syncthreads();
    for (int off = 128; off > 0; off >>= 1) {
        if (tid < off)
            #pragma unroll
            for (int o = 0; o < 10; o++) red[o][tid] += red[o][tid + off];
        __syncthreads();
    }
    if (tid < 10) out[b * 10 + tid] = red[tid][0] + fcb[tid];
}

// ------------------------------------------------------- launcher
extern "C" void kernel_launch(void* const* d_in, const int* in_sizes, int n_in,
                              void* d_out, int out_size, void* d_ws, size_t ws_size,
                              hipStream_t stream) {
    const int*   sent = (const int*)d_in[0];
    const float* emb  = (const float*)d_in[1];
    const float* wih0 = (const float*)d_in[2];
    const float* whh0 = (const float*)d_in[3];
    const float* bih0 = (const float*)d_in[4];
    const float* bhh0 = (const float*)d_in[5];
    const float* wih1 = (const float*)d_in[6];
    const float* whh1 = (const float*)d_in[7];
    const float* bih1 = (const float*)d_in[8];
    const float* bhh1 = (const float*)d_in[9];
    const float* fcw  = (const float*)d_in[10];
    const float* fcb  = (const float*)d_in[11];
    float* outp = (float*)d_out;

    // workspace layout — ~132.4 MB (proven-safe envelope: >=134.5 MB)
    char*  ws  = (char*)d_ws;
    float* xg  = (float*)(ws);                           // 2*CT*G3*B*4 = 50,331,648 B
    u16*   x1  = (u16*)(ws + 50331648L);                 // B*T*1024*2  = 67,108,864 B
    float* h32 = (float*)(ws + 50331648L + 67108864L);   // 2*B*H*4     =    262,144 B
    u32*   slt = (u32*)(ws + 50331648L + 67108864L + 262144L);   // slots 524,288 B
    u16*   wbf = (u16*)(ws + 50331648L + 67108864L + 262144L + 524288L);
    u16* wih0b = wbf;                      // 2*1536*256  =   786,432 el
    u16* wih1b = wbf + 786432L;            // 2*1536*1024 = 3,145,728 el
    u16* whh0b = wbf + 786432L + 3145728L; // 2*1536*512  = 1,572,864 el
    u16* whh1b = whh0b + 1572864L;         // 1,572,864 el

    // fused weight convert + layer-0 init (1 launch instead of 5)
    k_prep<<<512, 256, 0, stream>>>(wih0, wih1, whh0, whh1,
                                    wih0b, wih1b, whh0b, whh1b, h32, slt);

    dim3 gg(32, 12, 2);      // GEMM: 32 m-blocks x 12 n-tiles x 2 dirs
    // recurrence: 1-D grid of 256 so dom = bid&7 groups each domain on one XCD

    // ---- layer 0 (embedding gather fused into GEMM A-staging) ----
    for (int c = 0; c < T / CT; c++) {
        k_gemm_xg<<<gg, 256, 0, stream>>>(sent, emb, 1, wih0b, bih0, xg, E, c);
        k_chunk<<<256, 64, 0, stream>>>(whh0b, bhh0, xg, h32, slt, c, x1, 1);
    }

    // ---- layer 1 (A = x1, already bf16) ----
    k_init<<<512, 256, 0, stream>>>(h32, slt);
    for (int c = 0; c < T / CT; c++) {
        k_gemm_xg<<<gg, 256, 0, stream>>>(sent, x1, 0, wih1b, bih1, xg, 2 * H, c);
        k_chunk<<<256, 64, 0, stream>>>(whh1b, bhh1, xg, h32, slt, c, (u16*)nullptr, 0);
    }

    k_fc<<<B, 256, 0, stream>>>(h32, fcw, fcb, outp);
}

// Round 17
// 2833.379 us; speedup vs baseline: 1.0881x; 1.0211x over previous
//
#include <hip/hip_runtime.h>
#include <stdint.h>

#define H   512
#define B   64
#define T   512
#define E   256
#define G3  1536   // 3*H
#define CT  64     // time-chunk length (T/CT = 8 chunks)
#define NBG 4      // independent batch groups (16 batches each)
#define NUG 32     // unit blocks per direction (16 units each)

typedef short s16;
typedef unsigned short u16;
typedef unsigned int u32;
typedef __attribute__((ext_vector_type(8))) short   short8;
typedef __attribute__((ext_vector_type(4))) float   f32x4;
typedef __attribute__((ext_vector_type(4))) unsigned int u32x4;
typedef __attribute__((ext_vector_type(2))) unsigned int u32x2;
typedef __bf16 bf8_t __attribute__((ext_vector_type(8)));

__device__ __forceinline__ u16 f2b(float f) {
    union { float f; unsigned int i; } v; v.f = f;
    unsigned int r = v.i + 0x7FFF + ((v.i >> 16) & 1);
    return (u16)(r >> 16);
}
__device__ __forceinline__ float sigm(float x)  { return 1.f / (1.f + __expf(-x)); }
__device__ __forceinline__ float tanhs(float x) { return 1.f - 2.f / (1.f + __expf(2.f * x)); }

// ------------------------------------------------------- fused prep: weight cvt + layer-0 init
__global__ void k_prep(const float* __restrict__ wih0, const float* __restrict__ wih1,
                       const float* __restrict__ whh0, const float* __restrict__ whh1,
                       u16* __restrict__ wih0b, u16* __restrict__ wih1b,
                       u16* __restrict__ whh0b, u16* __restrict__ whh1b,
                       float* __restrict__ h32, u32* __restrict__ slots) {
    long i = (long)blockIdx.x * 256 + threadIdx.x;
    long stride = (long)gridDim.x * 256;
    for (long j = i; j < 786432L;  j += stride) wih0b[j] = f2b(wih0[j]);
    for (long j = i; j < 3145728L; j += stride) wih1b[j] = f2b(wih1[j]);
    for (long j = i; j < 1572864L; j += stride) whh0b[j] = f2b(whh0[j]);
    for (long j = i; j < 1572864L; j += stride) whh1b[j] = f2b(whh1[j]);
    for (long j = i; j < 131072L;  j += stride) slots[j] = 0;     // stamp 0 + h_0 = 0
    for (long j = i; j < 65536L;   j += stride) h32[j] = 0.f;     // fp32 carry
}

// ------------------------------------------------------- init h32/slots (between layers)
__global__ void k_init(float* __restrict__ h32, u32* __restrict__ slots) {
    int i = blockIdx.x * 256 + threadIdx.x;      // 131072 u32 = 512 KB slot buffer
    slots[i] = 0;                                 // stamp 0 + h=0 (initial state h_0)
    if (i < 65536) h32[i] = 0.f;                 // 2 dirs * B*H fp32 carry
}

// ------------------------------------------------------- xg chunk GEMM (MFMA)
// Writes xgT[d][tl][n][b] (fp32) = A[b,t,:K] . Wbf[d][n][:K] + bih[d][n]
// m-mapping: b = m&63, tl = m>>6. MFMA operands SWAPPED -> coalesced C stores.
#define BM 128
#define BN 128
#define BK 32

__global__ __launch_bounds__(256)
void k_gemm_xg(const int* __restrict__ sent, const void* __restrict__ Abuf, int aIsF32,
               const u16* __restrict__ Wbf, const float* __restrict__ bih,
               float* __restrict__ xgT, int K, int c) {
    int d  = blockIdx.z;
    int t0 = d ? (T - (c + 1) * CT) : c * CT;
    const u16* Bw = Wbf + (long)d * G3 * K;
    const float* bias = bih + (long)d * G3;
    float* C = xgT + (long)d * (long)CT * G3 * B;

    __shared__ __align__(16) s16 lA[BM * BK];
    __shared__ __align__(16) s16 lB[BN * BK];

    int tid  = threadIdx.x;
    int lane = tid & 63;
    int wv   = tid >> 6;
    int wm   = wv >> 1, wn = wv & 1;
    int q    = lane >> 4, r16 = lane & 15;

    long m0 = (long)blockIdx.x * BM;
    long n0 = (long)blockIdx.y * BN;

    const float* rowAf[2];
    const s16*   rowAh[2];
    const u16*   rowB[2];
    #pragma unroll
    for (int i = 0; i < 2; i++) {
        int ch = tid + i * 256;
        int r  = ch >> 2, cc = (ch & 3) * 8;
        long m = m0 + r;
        int  bb_ = (int)(m & 63), tl = (int)(m >> 6);   // m = (tl<<6)|b
        int  t  = t0 + tl;
        if (aIsF32) rowAf[i] = (const float*)Abuf + (long)sent[bb_ * T + t] * K + cc;
        else        rowAh[i] = (const s16*)Abuf + ((long)bb_ * T + t) * K + cc;
        rowB[i] = Bw + (n0 + r) * K + cc;
    }

    f32x4 acc[4][4];
    #pragma unroll
    for (int i = 0; i < 4; i++)
        #pragma unroll
        for (int j = 0; j < 4; j++) acc[i][j] = (f32x4){0.f, 0.f, 0.f, 0.f};

    for (long k0 = 0; k0 < K; k0 += BK) {
        #pragma unroll
        for (int i = 0; i < 2; i++) {
            if (aIsF32) {
                float4 v0 = *(const float4*)(rowAf[i] + k0);
                float4 v1 = *(const float4*)(rowAf[i] + k0 + 4);
                short8 pk;
                pk[0] = (s16)f2b(v0.x); pk[1] = (s16)f2b(v0.y);
                pk[2] = (s16)f2b(v0.z); pk[3] = (s16)f2b(v0.w);
                pk[4] = (s16)f2b(v1.x); pk[5] = (s16)f2b(v1.y);
                pk[6] = (s16)f2b(v1.z); pk[7] = (s16)f2b(v1.w);
                ((short8*)lA)[tid + i * 256] = pk;
            } else {
                ((short8*)lA)[tid + i * 256] = *(const short8*)(rowAh[i] + k0);
            }
            ((short8*)lB)[tid + i * 256] = *(const short8*)((const s16*)rowB[i] + k0);
        }
        __syncthreads();

        bf8_t af[4], bf[4];
        #pragma unroll
        for (int mt = 0; mt < 4; mt++)
            af[mt] = ((const bf8_t*)lA)[(wm * 64 + mt * 16 + r16) * 4 + q];
        #pragma unroll
        for (int nt = 0; nt < 4; nt++)
            bf[nt] = ((const bf8_t*)lB)[(wn * 64 + nt * 16 + r16) * 4 + q];
        #pragma unroll
        for (int mt = 0; mt < 4; mt++)
            #pragma unroll
            for (int nt = 0; nt < 4; nt++)
                acc[mt][nt] = __builtin_amdgcn_mfma_f32_16x16x32_bf16(
                                  bf[nt], af[mt], acc[mt][nt], 0, 0, 0);   // swapped
        __syncthreads();
    }

    // D layout (swapped): row (q*4+rg) -> n-sub, col (r16) -> m-sub
    #pragma unroll
    for (int nt = 0; nt < 4; nt++) {
        f32x4 bv = *(const f32x4*)(bias + n0 + wn * 64 + nt * 16 + q * 4);
        #pragma unroll
        for (int mt = 0; mt < 4; mt++) {
            long m = m0 + wm * 64 + mt * 16 + r16;
            long tl = m >> 6, b = m & 63;
            #pragma unroll
            for (int rg = 0; rg < 4; rg++) {
                long n = n0 + wn * 64 + nt * 16 + q * 4 + rg;
                C[(tl * G3 + n) * B + b] = acc[mt][nt][rg] + bv[rg];
            }
        }
    }
}

// bulk load macro: 32 x dwordx4, each instr 1024 lane-contiguous bytes, scope SC
#define BULK(SC) \
    asm volatile( \
        "global_load_dwordx4 %0,  %16, off " SC "\n\t" \
        "global_load_dwordx4 %1,  %16, off offset:1024 " SC "\n\t" \
        "global_load_dwordx4 %2,  %16, off offset:2048 " SC "\n\t" \
        "global_load_dwordx4 %3,  %16, off offset:3072 " SC "\n\t" \
        "global_load_dwordx4 %4,  %17, off " SC "\n\t" \
        "global_load_dwordx4 %5,  %17, off offset:1024 " SC "\n\t" \
        "global_load_dwordx4 %6,  %17, off offset:2048 " SC "\n\t" \
        "global_load_dwordx4 %7,  %17, off offset:3072 " SC "\n\t" \
        "global_load_dwordx4 %8,  %18, off " SC "\n\t" \
        "global_load_dwordx4 %9,  %18, off offset:1024 " SC "\n\t" \
        "global_load_dwordx4 %10, %18, off offset:2048 " SC "\n\t" \
        "global_load_dwordx4 %11, %18, off offset:3072 " SC "\n\t" \
        "global_load_dwordx4 %12, %19, off " SC "\n\t" \
        "global_load_dwordx4 %13, %19, off offset:1024 " SC "\n\t" \
        "global_load_dwordx4 %14, %19, off offset:2048 " SC "\n\t" \
        "global_load_dwordx4 %15, %19, off offset:3072 " SC \
        : "=&v"(p0),"=&v"(p1),"=&v"(p2),"=&v"(p3), \
          "=&v"(p4),"=&v"(p5),"=&v"(p6),"=&v"(p7), \
          "=&v"(p8),"=&v"(p9),"=&v"(p10),"=&v"(p11), \
          "=&v"(p12),"=&v"(p13),"=&v"(p14),"=&v"(p15) \
        : "v"(qa0), "v"(qa1), "v"(qa2), "v"(qa3) \
        : "memory"); \
    asm volatile( \
        "global_load_dwordx4 %0,  %16, off " SC "\n\t" \
        "global_load_dwordx4 %1,  %16, off offset:1024 " SC "\n\t" \
        "global_load_dwordx4 %2,  %16, off offset:2048 " SC "\n\t" \
        "global_load_dwordx4 %3,  %16, off offset:3072 " SC "\n\t" \
        "global_load_dwordx4 %4,  %17, off " SC "\n\t" \
        "global_load_dwordx4 %5,  %17, off offset:1024 " SC "\n\t" \
        "global_load_dwordx4 %6,  %17, off offset:2048 " SC "\n\t" \
        "global_load_dwordx4 %7,  %17, off offset:3072 " SC "\n\t" \
        "global_load_dwordx4 %8,  %18, off " SC "\n\t" \
        "global_load_dwordx4 %9,  %18, off offset:1024 " SC "\n\t" \
        "global_load_dwordx4 %10, %18, off offset:2048 " SC "\n\t" \
        "global_load_dwordx4 %11, %18, off offset:3072 " SC "\n\t" \
        "global_load_dwordx4 %12, %19, off " SC "\n\t" \
        "global_load_dwordx4 %13, %19, off offset:1024 " SC "\n\t" \
        "global_load_dwordx4 %14, %19, off offset:2048 " SC "\n\t" \
        "global_load_dwordx4 %15, %19, off offset:3072 " SC "\n\t" \
        "s_waitcnt vmcnt(0)" \
        : "=&v"(p16),"=&v"(p17),"=&v"(p18),"=&v"(p19), \
          "=&v"(p20),"=&v"(p21),"=&v"(p22),"=&v"(p23), \
          "=&v"(p24),"=&v"(p25),"=&v"(p26),"=&v"(p27), \
          "=&v"(p28),"=&v"(p29),"=&v"(p30),"=&v"(p31) \
        : "v"(qa4), "v"(qa5), "v"(qa6), "v"(qa7) \
        : "memory");

// ------------------------------------------------------- wave-autonomous chunk recurrence
// 1-D grid of 256 single-wave blocks: dom = bid&7 -> (d,bg); ug = bid>>3.
// Single-XCD domains under round-robin placement; slot traffic in local L2.
// Protocol identical to R12/R14/R15/R16 (dual-store sc0 + sc0 sc1; sc0 bulk
// verify-retry with sticky sc1 escalation). Calibrated de-convoy sleeps
// (stepped again per the linear response through R15/R16):
//  (a) s_sleep(12) pre-poll (~0.32us) — cover the producer store-landing window;
//  (b) s_sleep(6) backoff between failed rounds.
// Pure delays: no sync-semantics change, cannot hang.
__global__ __launch_bounds__(64, 1)
void k_chunk(const u16* __restrict__ Whhbf, const float* __restrict__ bhh,
             const float* __restrict__ xgT, float* __restrict__ h32,
             u32* __restrict__ slots, int c, u16* __restrict__ x1out, int writeX1) {
    int bid = blockIdx.x;
    int dom = bid & 7;                   // sync domain: one XCD under round-robin
    int ug  = bid >> 3;                  // unit group: units ug*16..+15
    int d   = dom >> 2;
    int bg  = dom & 3;
    int lane = threadIdx.x;              // 0..63
    int q = lane >> 4, cc = lane & 15;
    int u0 = ug * 16;
    int bgl = bg * 16 + cc;              // this lane's batch (D-col side)

    const u16* W    = Whhbf + (long)d * G3 * H;
    const float* bb = bhh + (long)d * G3;
    const float* xgf = xgT + (long)d * (long)CT * G3 * B;
    float* h32d = h32 + (long)d * B * H;
    char* slotbase = (char*)slots;

    // ---- weight slice as registers (A-frag) ----
    bf8_t w[3][16];
    #pragma unroll
    for (int gate = 0; gate < 3; gate++)
        #pragma unroll
        for (int kc = 0; kc < 16; kc++)
            w[gate][kc] = *(const bf8_t*)(W + (long)(gate * H + u0 + cc) * H + kc * 32 + q * 8);

    // per-unit biases, f32x4 over rg (units u0+q*4..+3)
    f32x4 brv = *(const f32x4*)(bb + u0 + q * 4);
    f32x4 bzv = *(const f32x4*)(bb + H + u0 + q * 4);
    f32x4 bnv = *(const f32x4*)(bb + 2 * H + u0 + q * 4);

    // fp32 h-carry: lane holds h[b=bgl][u0+q*4+rg] -> f32x4
    f32x4 hp = *(const f32x4*)(h32d + (long)bgl * H + u0 + q * 4);

    // producer slot byte offset (within a 32KB (d,parity,bg) block)
    int jw = ug * 4 + q;                 // unit quad index of this lane's 4 units
    long off_wr = (long)((jw >> 3) * 2 + (jw & 1)) * 1024
                + (long)((jw >> 1) & 3) * 256 + cc * 16;

    int base = c * CT;
    bool fast = true;                    // sticky: escalate to sc1 reads on trouble

    for (int sl = 0; sl < CT; sl++) {
        int s    = base + sl;
        int tl   = d ? (CT - 1 - sl) : sl;
        int time = d ? (T - 1 - s) : s;
        int tgt  = s;
        u32 st1  = (u32)(s + 1);

        // xg loads: issued first; latency hidden under the pre-poll sleep + bulk.
        const float* xgb = xgf + ((long)tl * G3 + u0 + q * 4) * B + bgl;
        float xr[4], xz[4], xn[4];
        #pragma unroll
        for (int jj = 0; jj < 4; jj++) {
            xr[jj] = xgb[(long)jj * B];
            xz[jj] = xgb[(long)H * B + (long)jj * B];
            xn[jj] = xgb[(long)2 * H * B + (long)jj * B];
        }

        const char* domb = slotbase + (long)(((d * 2 + (s & 1)) * 4 + bg) * 32768);
        const char* pb  = domb + lane * 16;
        const char* qa0 = pb;
        const char* qa1 = pb + 4096;
        const char* qa2 = pb + 8192;
        const char* qa3 = pb + 12288;
        const char* qa4 = pb + 16384;
        const char* qa5 = pb + 20480;
        const char* qa6 = pb + 24576;
        const char* qa7 = pb + 28672;
        u32x4 p0,p1,p2,p3,p4,p5,p6,p7,p8,p9,p10,p11,p12,p13,p14,p15;
        u32x4 p16,p17,p18,p19,p20,p21,p22,p23,p24,p25,p26,p27,p28,p29,p30,p31;

        if (sl > 0) __builtin_amdgcn_s_sleep(12);  // (a) cover store-landing window
        int fails = 0;
        for (;;) {
            // ---- fused bulk load + full stamp verify (retry on straggler) ----
            if (fast) { BULK("sc0") }
            else      { BULK("sc0 sc1") }
            __builtin_amdgcn_sched_barrier(0);   // stamp checks must not hoist above vmcnt
            int mn = min((int)p0[1], (int)p0[3]);
            #define MN2(x) mn = min(mn, min((int)x[1], (int)x[3]));
            MN2(p1)  MN2(p2)  MN2(p3)  MN2(p4)  MN2(p5)  MN2(p6)  MN2(p7)
            MN2(p8)  MN2(p9)  MN2(p10) MN2(p11) MN2(p12) MN2(p13) MN2(p14) MN2(p15)
            MN2(p16) MN2(p17) MN2(p18) MN2(p19) MN2(p20) MN2(p21) MN2(p22) MN2(p23)
            MN2(p24) MN2(p25) MN2(p26) MN2(p27) MN2(p28) MN2(p29) MN2(p30) MN2(p31)
            #undef MN2
            if (__all(mn >= tgt)) break;
            if (++fails > 8) fast = false;   // sticky escalation to durable path
            __builtin_amdgcn_s_sleep(6);     // (b) backoff: yield L2 to stores
        }

        // ---- MFMA (swapped): A = W regs, B = h frags from slot pairs ----
        f32x4 aR = (f32x4){0.f,0.f,0.f,0.f};
        f32x4 aZ = (f32x4){0.f,0.f,0.f,0.f};
        f32x4 aN = (f32x4){0.f,0.f,0.f,0.f};
        #define STEP_KC(kc, A_, B_) { \
            u32x4 fw = (u32x4){A_[0], A_[2], B_[0], B_[2]}; \
            bf8_t hb = __builtin_bit_cast(bf8_t, fw); \
            aR = __builtin_amdgcn_mfma_f32_16x16x32_bf16(w[0][kc], hb, aR, 0, 0, 0); \
            aZ = __builtin_amdgcn_mfma_f32_16x16x32_bf16(w[1][kc], hb, aZ, 0, 0, 0); \
            aN = __builtin_amdgcn_mfma_f32_16x16x32_bf16(w[2][kc], hb, aN, 0, 0, 0); }
        STEP_KC(0,  p0,  p1)  STEP_KC(1,  p2,  p3)  STEP_KC(2,  p4,  p5)  STEP_KC(3,  p6,  p7)
        STEP_KC(4,  p8,  p9)  STEP_KC(5,  p10, p11) STEP_KC(6,  p12, p13) STEP_KC(7,  p14, p15)
        STEP_KC(8,  p16, p17) STEP_KC(9,  p18, p19) STEP_KC(10, p20, p21) STEP_KC(11, p22, p23)
        STEP_KC(12, p24, p25) STEP_KC(13, p26, p27) STEP_KC(14, p28, p29) STEP_KC(15, p30, p31)
        #undef STEP_KC

        // ---- gates: lane (q,cc) -> batch bgl, units u0+q*4+rg ----
        float hh[4];
        #pragma unroll
        for (int rg = 0; rg < 4; rg++) {
            float r = sigm(xr[rg] + aR[rg] + brv[rg]);
            float z = sigm(xz[rg] + aZ[rg] + bzv[rg]);
            float n = tanhs(xn[rg] + r * (aN[rg] + bnv[rg]));
            hh[rg] = (1.f - z) * n + z * hp[rg];
        }
        hp = (f32x4){hh[0], hh[1], hh[2], hh[3]};

        // ---- dual-store self-certifying slot (parity (s+1)&1, stamp s+1) ----
        u32 w0 = (u32)f2b(hh[0]) | ((u32)f2b(hh[1]) << 16);
        u32 w1 = (u32)f2b(hh[2]) | ((u32)f2b(hh[3]) << 16);
        u32x4 sv = (u32x4){w0, st1, w1, st1};
        char* ps = slotbase + (long)(((d * 2 + ((s + 1) & 1)) * 4 + bg) * 32768) + off_wr;
        asm volatile("global_store_dwordx4 %0, %1, off sc0"
                     :: "v"(ps), "v"(sv) : "memory");        // fast copy (local L2)
        asm volatile("global_store_dwordx4 %0, %1, off sc0 sc1"
                     :: "v"(ps), "v"(sv) : "memory");        // durable copy (MALL)

        if (writeX1) {
            u32x2 xv = (u32x2){w0, w1};   // 4 consecutive units at batch bgl
            *(u32x2*)(x1out + ((long)bgl * T + time) * 1024 + d * H + u0 + q * 4) = xv;
        }
        // NO drain, NO flag: next step's bulk verify certifies visibility.
    }

    // spill fp32 carry for next chunk dispatch / k_fc (kernel-boundary coherence)
    *(f32x4*)(h32d + (long)bgl * H + u0 + q * 4) = hp;
}
#undef BULK

// ------------------------------------------------------- final FC (fp32)
__global__ __launch_bounds__(256)
void k_fc(const float* __restrict__ h32, const float* __restrict__ fcw,
          const float* __restrict__ fcb, float* __restrict__ out) {
    int b   = blockIdx.x;
    int tid = threadIdx.x;
    float p[10];
    #pragma unroll
    for (int o = 0; o < 10; o++) p[o] = 0.f;
    for (int k = tid; k < 1024; k += 256) {
        int dd = k >> 9, kk = k & 511;
        float hv = h32[(long)dd * B * H + (long)b * H + kk];
        #pragma unroll
        for (int o = 0; o < 10; o++) p[o] += hv * fcw[o * 1024 + k];
    }
    __shared__ float red[10][256];
    #pragma unroll
    for (int o = 0; o < 10; o++) red[o][tid] = p[o];
    __syncthreads();
    for (int off = 128; off > 0; off >>= 1) {
        if (tid < off)
            #pragma unroll
            for (int o = 0; o < 10; o++) red[o][tid] += red[o][tid + off];
        __syncthreads();
    }
    if (tid < 10) out[b * 10 + tid] = red[tid][0] + fcb[tid];
}

// ------------------------------------------------------- launcher
extern "C" void kernel_launch(void* const* d_in, const int* in_sizes, int n_in,
                              void* d_out, int out_size, void* d_ws, size_t ws_size,
                              hipStream_t stream) {
    const int*   sent = (const int*)d_in[0];
    const float* emb  = (const float*)d_in[1];
    const float* wih0 = (const float*)d_in[2];
    const float* whh0 = (const float*)d_in[3];
    const float* bih0 = (const float*)d_in[4];
    const float* bhh0 = (const float*)d_in[5];
    const float* wih1 = (const float*)d_in[6];
    const float* whh1 = (const float*)d_in[7];
    const float* bih1 = (const float*)d_in[8];
    const float* bhh1 = (const float*)d_in[9];
    const float* fcw  = (const float*)d_in[10];
    const float* fcb  = (const float*)d_in[11];
    float* outp = (float*)d_out;

    // workspace layout — ~132.4 MB (proven-safe envelope: >=134.5 MB)
    char*  ws  = (char*)d_ws;
    float* xg  = (float*)(ws);                           // 2*CT*G3*B*4 = 50,331,648 B
    u16*   x1  = (u16*)(ws + 50331648L);                 // B*T*1024*2  = 67,108,864 B
    float* h32 = (float*)(ws + 50331648L + 67108864L);   // 2*B*H*4     =    262,144 B
    u32*   slt = (u32*)(ws + 50331648L + 67108864L + 262144L);   // slots 524,288 B
    u16*   wbf = (u16*)(ws + 50331648L + 67108864L + 262144L + 524288L);
    u16* wih0b = wbf;                      // 2*1536*256  =   786,432 el
    u16* wih1b = wbf + 786432L;            // 2*1536*1024 = 3,145,728 el
    u16* whh0b = wbf + 786432L + 3145728L; // 2*1536*512  = 1,572,864 el
    u16* whh1b = whh0b + 1572864L;         // 1,572,864 el

    // fused weight convert + layer-0 init (1 launch instead of 5)
    k_prep<<<512, 256, 0, stream>>>(wih0, wih1, whh0, whh1,
                                    wih0b, wih1b, whh0b, whh1b, h32, slt);

    dim3 gg(32, 12, 2);      // GEMM: 32 m-blocks x 12 n-tiles x 2 dirs
    // recurrence: 1-D grid of 256 so dom = bid&7 groups each domain on one XCD

    // ---- layer 0 (embedding gather fused into GEMM A-staging) ----
    for (int c = 0; c < T / CT; c++) {
        k_gemm_xg<<<gg, 256, 0, stream>>>(sent, emb, 1, wih0b, bih0, xg, E, c);
        k_chunk<<<256, 64, 0, stream>>>(whh0b, bhh0, xg, h32, slt, c, x1, 1);
    }

    // ---- layer 1 (A = x1, already bf16) ----
    k_init<<<512, 256, 0, stream>>>(h32, slt);
    for (int c = 0; c < T / CT; c++) {
        k_gemm_xg<<<gg, 256, 0, stream>>>(sent, x1, 0, wih1b, bih1, xg, 2 * H, c);
        k_chunk<<<256, 64, 0, stream>>>(whh1b, bhh1, xg, h32, slt, c, (u16*)nullptr, 0);
    }

    k_fc<<<B, 256, 0, stream>>>(h32, fcw, fcb, outp);
}